// Round 1
// baseline (296.434 us; speedup 1.0000x reference)
//
#include <hip/hip_runtime.h>
#include <stdint.h>

#define IDIM 2048
#define HDIM 2048
#define CDIM 4096
#define BDIM 4096
#define KDIM 4096

typedef float f32x4 __attribute__((ext_vector_type(4)));
typedef short s16x8 __attribute__((ext_vector_type(8)));
typedef unsigned short u16;
typedef u16 u16x8 __attribute__((ext_vector_type(8)));

__device__ __forceinline__ u16 f2bf(float f) {
    union { float f; uint32_t u; } v; v.f = f;
    uint32_t r = v.u + 0x7fffu + ((v.u >> 16) & 1u);  // round-to-nearest-even
    return (u16)(r >> 16);
}

__device__ __forceinline__ void gload_lds16(const void* g, void* l) {
    __builtin_amdgcn_global_load_lds(
        (__attribute__((address_space(1))) void*)g,
        (__attribute__((address_space(3))) void*)l,
        16, 0, 0);
}

// flat f32 -> bf16 convert, 8 elements per thread
__global__ void cvt_bf16_kernel(const float* __restrict__ src, u16* __restrict__ dst,
                                int ngroups) {
    int i = blockIdx.x * blockDim.x + threadIdx.x;
    if (i >= ngroups) return;
    const float4* s4 = (const float4*)src;
    float4 v0 = s4[2 * i], v1 = s4[2 * i + 1];
    u16x8 o;
    o[0] = f2bf(v0.x); o[1] = f2bf(v0.y); o[2] = f2bf(v0.z); o[3] = f2bf(v0.w);
    o[4] = f2bf(v1.x); o[5] = f2bf(v1.y); o[6] = f2bf(v1.z); o[7] = f2bf(v1.w);
    ((u16x8*)dst)[i] = o;
}

// combined = [x, h] as bf16 [BDIM][CDIM]; also pre-fill new_combined's x half
__global__ void pack_combined_kernel(const float* __restrict__ x, const float* __restrict__ h,
                                     u16* __restrict__ comb, u16* __restrict__ newc) {
    int i = blockIdx.x * blockDim.x + threadIdx.x;  // one group of 8 elems
    if (i >= BDIM * (CDIM / 8)) return;
    int b = i >> 9;              // CDIM/8 == 512
    int c = (i & 511) * 8;
    const float* src = (c < IDIM) ? (x + (size_t)b * IDIM + c)
                                  : (h + (size_t)b * HDIM + (c - IDIM));
    float4 v0 = ((const float4*)src)[0], v1 = ((const float4*)src)[1];
    u16x8 o;
    o[0] = f2bf(v0.x); o[1] = f2bf(v0.y); o[2] = f2bf(v0.z); o[3] = f2bf(v0.w);
    o[4] = f2bf(v1.x); o[5] = f2bf(v1.y); o[6] = f2bf(v1.z); o[7] = f2bf(v1.w);
    *(u16x8*)(comb + (size_t)b * CDIM + c) = o;
    if (c < IDIM) *(u16x8*)(newc + (size_t)b * CDIM + c) = o;
}

// C = A[M,K] * B[N,K]^T, bf16 inputs, f32 accum, fused epilogues.
// m97 structure: 128x128 tile, BK=64, 4 waves (2x2), each wave 64x64 = 4x4 frags
// of 16x16x32 MFMA. global_load_lds w=16, XOR-swizzled source, swizzled ds_read.
// EP==1: v=sigmoid(acc+bias); col<HDIM -> newc[r][IDIM+col]=bf16(h*v);
//        col>=HDIM -> Sout[r][col-HDIM]=v
// EP==2: p=tanh(acc+bias0); s=Sout[r][col]; Sout[r][col]=h*(1-s)+p*s
template <int EP>
__global__ void gemm_bt(const u16* __restrict__ A, const u16* __restrict__ Bm,
                        const float* __restrict__ h,
                        const float* __restrict__ bias0, const float* __restrict__ bias1,
                        float* __restrict__ Sout, u16* __restrict__ newc) {
    constexpr int BM = 128, BK = 64;
    const int tid  = threadIdx.x;
    const int lane = tid & 63;
    const int wave = tid >> 6;
    const int wr = wave >> 1, wc = wave & 1;
    const int bm = blockIdx.y * BM;
    const int bn = blockIdx.x * BM;

    __shared__ __align__(16) u16 lA[BM * BK];
    __shared__ __align__(16) u16 lB[BM * BK];

    f32x4 acc[4][4] = {};

    const int srow = wave * 32 + (lane >> 3);       // staged row (per i: +8*i)
    const int sg   = (lane & 7) ^ (lane >> 3);      // swizzled source k-slot

    auto stage = [&](int k0) {
        #pragma unroll
        for (int i = 0; i < 4; ++i) {
            const int r = srow + i * 8;
            gload_lds16(A  + (size_t)(bm + r) * KDIM + k0 + sg * 8,
                        &lA[(wave * 32 + i * 8) * 64]);
            gload_lds16(Bm + (size_t)(bn + r) * KDIM + k0 + sg * 8,
                        &lB[(wave * 32 + i * 8) * 64]);
        }
    };

    stage(0);
    constexpr int NT = KDIM / BK;
    for (int kt = 0; kt < NT; ++kt) {
        __syncthreads();   // drains global_load_lds (vmcnt) + all waves ready
        #pragma unroll
        for (int ks = 0; ks < 2; ++ks) {
            s16x8 af[4], bfr[4];
            #pragma unroll
            for (int m = 0; m < 4; ++m) {
                const int row = wr * 64 + m * 16 + (lane & 15);
                const int j   = ks * 4 + (lane >> 4);
                af[m] = *(const s16x8*)&lA[row * 64 + ((j ^ (row & 7)) << 3)];
            }
            #pragma unroll
            for (int n = 0; n < 4; ++n) {
                const int row = wc * 64 + n * 16 + (lane & 15);
                const int j   = ks * 4 + (lane >> 4);
                bfr[n] = *(const s16x8*)&lB[row * 64 + ((j ^ (row & 7)) << 3)];
            }
            #pragma unroll
            for (int m = 0; m < 4; ++m)
                #pragma unroll
                for (int n = 0; n < 4; ++n)
                    acc[m][n] = __builtin_amdgcn_mfma_f32_16x16x32_bf16(
                        af[m], bfr[n], acc[m][n], 0, 0, 0);
        }
        __syncthreads();   // all reads done before restage
        if (kt + 1 < NT) stage((kt + 1) * BK);
    }

    // epilogue: D layout col = lane&15, row = (lane>>4)*4 + reg (m89-verified)
    #pragma unroll
    for (int m = 0; m < 4; ++m) {
        const int r0 = bm + wr * 64 + m * 16 + ((lane >> 4) << 2);
        #pragma unroll
        for (int n = 0; n < 4; ++n) {
            const int col = bn + wc * 64 + n * 16 + (lane & 15);
            #pragma unroll
            for (int j = 0; j < 4; ++j) {
                const int r = r0 + j;
                const float v = acc[m][n][j];
                if (EP == 1) {
                    const float bv = (col < HDIM) ? bias0[col] : bias1[col - HDIM];
                    const float sgm = 1.0f / (1.0f + __expf(-(v + bv)));
                    if (col < HDIM) {
                        const float hv = h[(size_t)r * HDIM + col];
                        newc[(size_t)r * CDIM + IDIM + col] = f2bf(hv * sgm);
                    } else {
                        Sout[(size_t)r * HDIM + (col - HDIM)] = sgm;
                    }
                } else {
                    const float p  = tanhf(v + bias0[col]);
                    const size_t idx = (size_t)r * HDIM + col;
                    const float s  = Sout[idx];
                    const float hv = h[idx];
                    Sout[idx] = hv * (1.0f - s) + p * s;
                }
            }
        }
    }
}

extern "C" void kernel_launch(void* const* d_in, const int* in_sizes, int n_in,
                              void* d_out, int out_size, void* d_ws, size_t ws_size,
                              hipStream_t stream) {
    (void)in_sizes; (void)n_in; (void)out_size; (void)ws_size;
    const float* x  = (const float*)d_in[0];
    const float* h  = (const float*)d_in[1];
    const float* Wu = (const float*)d_in[2];
    const float* bu = (const float*)d_in[3];
    const float* Ws = (const float*)d_in[4];
    const float* bs = (const float*)d_in[5];
    const float* Wp = (const float*)d_in[6];
    const float* bp = (const float*)d_in[7];
    float* out = (float*)d_out;

    // workspace layout (bf16 elements): 112 MB total
    u16* comb  = (u16*)d_ws;                            // [BDIM][CDIM]   32 MB
    u16* newc  = comb  + (size_t)BDIM * CDIM;           // [BDIM][CDIM]   32 MB
    u16* wpack = newc  + (size_t)BDIM * CDIM;           // [2*HDIM][CDIM] 32 MB
    u16* wpred = wpack + (size_t)2 * HDIM * CDIM;       // [HDIM][CDIM]   16 MB

    const int WG = 256;
    const int wgrp = (HDIM * CDIM) / 8;                 // 1M groups per weight
    cvt_bf16_kernel<<<wgrp / WG, WG, 0, stream>>>(Wu, wpack, wgrp);
    cvt_bf16_kernel<<<wgrp / WG, WG, 0, stream>>>(Ws, wpack + (size_t)HDIM * CDIM, wgrp);
    cvt_bf16_kernel<<<wgrp / WG, WG, 0, stream>>>(Wp, wpred, wgrp);
    const int cgrp = (BDIM * CDIM) / 8;                 // 2M groups
    pack_combined_kernel<<<cgrp / WG, WG, 0, stream>>>(x, h, comb, newc);

    // GEMM1: [x,h] @ [Wu;Ws]^T -> sigmoid -> updated (bf16 into newc) + S (f32 into out)
    gemm_bt<1><<<dim3(CDIM / 128, BDIM / 128), 256, 0, stream>>>(
        comb, wpack, h, bu, bs, out, newc);
    // GEMM2: [x,updated] @ Wp^T -> tanh -> h_new (f32 into out, reading S in place)
    gemm_bt<2><<<dim3(HDIM / 128, BDIM / 128), 256, 0, stream>>>(
        newc, wpred, h, bp, nullptr, out, nullptr);
}